// Round 3
// baseline (1872.374 us; speedup 1.0000x reference)
//
#include <hip/hip_runtime.h>
#include <hip/hip_bf16.h>

// LSTM autoencoder: B=256, T=512, IN=128, HID=64, LAT=16
// e1: LSTM(128->64) +relu ; e2: LSTM(64->16) +relu -> latent = last step
// d1: LSTM(16->64) on broadcast latent +relu ; d2: LSTM(64->128) (no relu)
//
// Persistent blocks, 1 block per batch row (grid=256 = #CUs).
// Thread = gate row (k-split where useful). Weights register-resident;
// h in LDS; c in update-thread registers. Projections fused into recurrence.
//
// OUTPUT IS FP32 (reference returns float32; "bf16" in the test label is
// hard-coded text, threshold = 2% * max|ref|).
//
// Buffer plan:
//   h_e1 -> d_out first half (33.5 MB; e2 consumes before d2 overwrites)
//   hd1  -> d_ws  (33.5 MB; round-1 run evidenced ws_size is sufficient)
//   lat  -> d_ws + 33.5MB (16 KB)
//   out  -> d_out, full 67 MB fp32, written only by d2 (no aliasing)

#define BB 256
#define TT 512

__device__ __forceinline__ float sigm(float v) { return 1.0f / (1.0f + __expf(-v)); }
__device__ __forceinline__ float tanh_(float v) { return 1.0f - 2.0f / (__expf(2.0f * v) + 1.0f); }

// ---------------- e1: IN=128, H=64, G=256. 512 threads = 256 gates x k-split 2.
__global__ __launch_bounds__(512) void k_e1(
    const float* __restrict__ x,
    const float* __restrict__ Wih, const float* __restrict__ Whh,
    const float* __restrict__ bih, const float* __restrict__ bhh,
    float* __restrict__ h_out /* [B,T,64] relu'd */)
{
  const int b   = blockIdx.x;
  const int tid = threadIdx.x;
  const int q   = tid >> 8;   // 0..1  k-slice
  const int g   = tid & 255;  // gate row

  __shared__ float h_lds[64];
  __shared__ float xbuf[2][128];
  __shared__ float part[2][256];

  float wx[64];
#pragma unroll
  for (int i = 0; i < 16; ++i) {
    float4 v = *reinterpret_cast<const float4*>(Wih + g * 128 + q * 64 + i * 4);
    wx[4*i] = v.x; wx[4*i+1] = v.y; wx[4*i+2] = v.z; wx[4*i+3] = v.w;
  }
  float wh[32];
#pragma unroll
  for (int i = 0; i < 8; ++i) {
    float4 v = *reinterpret_cast<const float4*>(Whh + g * 64 + q * 32 + i * 4);
    wh[4*i] = v.x; wh[4*i+1] = v.y; wh[4*i+2] = v.z; wh[4*i+3] = v.w;
  }
  const float bias = (q == 0) ? (bih[g] + bhh[g]) : 0.0f;

  const float* xrow = x + (size_t)b * (TT * 128);
  float* hrow = h_out + (size_t)b * (TT * 64);

  if (tid < 64) h_lds[tid] = 0.0f;
  if (tid < 128) xbuf[0][tid] = xrow[tid];
  float c = 0.0f;
  __syncthreads();

  for (int t = 0; t < TT; ++t) {
    const int cur = t & 1;
    float xn = 0.0f;
    if (tid < 128) {
      const int tn = (t + 1 < TT) ? (t + 1) : t;
      xn = xrow[tn * 128 + tid];
    }
    float a0 = 0.f, a1 = 0.f, a2 = 0.f, a3 = 0.f;
    const float4* xv = reinterpret_cast<const float4*>(&xbuf[cur][q * 64]);
#pragma unroll
    for (int i = 0; i < 16; ++i) {
      float4 v = xv[i];
      a0 = fmaf(wx[4*i],   v.x, a0);
      a1 = fmaf(wx[4*i+1], v.y, a1);
      a2 = fmaf(wx[4*i+2], v.z, a2);
      a3 = fmaf(wx[4*i+3], v.w, a3);
    }
    const float4* hv = reinterpret_cast<const float4*>(&h_lds[q * 32]);
#pragma unroll
    for (int i = 0; i < 8; ++i) {
      float4 v = hv[i];
      a0 = fmaf(wh[4*i],   v.x, a0);
      a1 = fmaf(wh[4*i+1], v.y, a1);
      a2 = fmaf(wh[4*i+2], v.z, a2);
      a3 = fmaf(wh[4*i+3], v.w, a3);
    }
    part[q][g] = bias + ((a0 + a1) + (a2 + a3));
    if (tid < 128) xbuf[cur ^ 1][tid] = xn;
    __syncthreads();
    if (tid < 64) {
      const float gi = part[0][tid]       + part[1][tid];
      const float gf = part[0][64 + tid]  + part[1][64 + tid];
      const float gg = part[0][128 + tid] + part[1][128 + tid];
      const float go = part[0][192 + tid] + part[1][192 + tid];
      c = sigm(gf) * c + sigm(gi) * tanh_(gg);
      const float h = sigm(go) * tanh_(c);
      h_lds[tid] = h;
      hrow[t * 64 + tid] = fmaxf(h, 0.0f);
    }
    __syncthreads();
  }
}

// ---------------- e2: IN=64, H=16, G=64. 256 threads = 64 gates x k-split 4.
__global__ __launch_bounds__(256) void k_e2(
    const float* __restrict__ xin /* [B,T,64] relu'd */,
    const float* __restrict__ Wih, const float* __restrict__ Whh,
    const float* __restrict__ bih, const float* __restrict__ bhh,
    float* __restrict__ lat /* [B,16] relu'd last step */)
{
  const int b   = blockIdx.x;
  const int tid = threadIdx.x;
  const int q   = tid >> 6;   // 0..3
  const int g   = tid & 63;

  __shared__ float h_lds[16];
  __shared__ float xbuf[2][64];
  __shared__ float part[4][64];

  float wx[16];
#pragma unroll
  for (int i = 0; i < 4; ++i) {
    float4 v = *reinterpret_cast<const float4*>(Wih + g * 64 + q * 16 + i * 4);
    wx[4*i] = v.x; wx[4*i+1] = v.y; wx[4*i+2] = v.z; wx[4*i+3] = v.w;
  }
  float wh[4];
  {
    float4 v = *reinterpret_cast<const float4*>(Whh + g * 16 + q * 4);
    wh[0] = v.x; wh[1] = v.y; wh[2] = v.z; wh[3] = v.w;
  }
  const float bias = (q == 0) ? (bih[g] + bhh[g]) : 0.0f;

  const float* xrow = xin + (size_t)b * (TT * 64);

  if (tid < 16) h_lds[tid] = 0.0f;
  if (tid < 64) xbuf[0][tid] = xrow[tid];
  float c = 0.0f;
  __syncthreads();

  for (int t = 0; t < TT; ++t) {
    const int cur = t & 1;
    float xn = 0.0f;
    if (tid < 64) {
      const int tn = (t + 1 < TT) ? (t + 1) : t;
      xn = xrow[tn * 64 + tid];
    }
    float a0 = 0.f, a1 = 0.f, a2 = 0.f, a3 = 0.f;
    const float4* xv = reinterpret_cast<const float4*>(&xbuf[cur][q * 16]);
#pragma unroll
    for (int i = 0; i < 4; ++i) {
      float4 v = xv[i];
      a0 = fmaf(wx[4*i],   v.x, a0);
      a1 = fmaf(wx[4*i+1], v.y, a1);
      a2 = fmaf(wx[4*i+2], v.z, a2);
      a3 = fmaf(wx[4*i+3], v.w, a3);
    }
    {
      float4 v = *reinterpret_cast<const float4*>(&h_lds[q * 4]);
      a0 = fmaf(wh[0], v.x, a0);
      a1 = fmaf(wh[1], v.y, a1);
      a2 = fmaf(wh[2], v.z, a2);
      a3 = fmaf(wh[3], v.w, a3);
    }
    part[q][g] = bias + ((a0 + a1) + (a2 + a3));
    if (tid < 64) xbuf[cur ^ 1][tid] = xn;
    __syncthreads();
    if (tid < 16) {
      const float gi = part[0][tid]      + part[1][tid]      + part[2][tid]      + part[3][tid];
      const float gf = part[0][16 + tid] + part[1][16 + tid] + part[2][16 + tid] + part[3][16 + tid];
      const float gg = part[0][32 + tid] + part[1][32 + tid] + part[2][32 + tid] + part[3][32 + tid];
      const float go = part[0][48 + tid] + part[1][48 + tid] + part[2][48 + tid] + part[3][48 + tid];
      c = sigm(gf) * c + sigm(gi) * tanh_(gg);
      const float h = sigm(go) * tanh_(c);
      h_lds[tid] = h;
      if (t == TT - 1) lat[b * 16 + tid] = fmaxf(h, 0.0f);
    }
    __syncthreads();
  }
}

// ---------------- d1: IN=16 (constant latent), H=64, G=256. 512 threads = 256 x 2.
__global__ __launch_bounds__(512) void k_d1(
    const float* __restrict__ lat /* [B,16] */,
    const float* __restrict__ Wih, const float* __restrict__ Whh,
    const float* __restrict__ bih, const float* __restrict__ bhh,
    float* __restrict__ h_out /* [B,T,64] relu'd */)
{
  const int b   = blockIdx.x;
  const int tid = threadIdx.x;
  const int q   = tid >> 8;
  const int g   = tid & 255;

  __shared__ float h_lds[64];
  __shared__ float lat_lds[16];
  __shared__ float part[2][256];

  float wh[32];
#pragma unroll
  for (int i = 0; i < 8; ++i) {
    float4 v = *reinterpret_cast<const float4*>(Whh + g * 64 + q * 32 + i * 4);
    wh[4*i] = v.x; wh[4*i+1] = v.y; wh[4*i+2] = v.z; wh[4*i+3] = v.w;
  }
  if (tid < 16) lat_lds[tid] = lat[b * 16 + tid];
  if (tid < 64) h_lds[tid] = 0.0f;
  float c = 0.0f;
  __syncthreads();

  // constant input projection (computed once; q==0 slice holds it all)
  float g0 = 0.0f;
  if (q == 0) {
    g0 = bih[g] + bhh[g];
#pragma unroll
    for (int i = 0; i < 16; ++i) g0 = fmaf(Wih[g * 16 + i], lat_lds[i], g0);
  }

  float* hrow = h_out + (size_t)b * (TT * 64);

  for (int t = 0; t < TT; ++t) {
    float a0 = 0.f, a1 = 0.f, a2 = 0.f, a3 = 0.f;
    const float4* hv = reinterpret_cast<const float4*>(&h_lds[q * 32]);
#pragma unroll
    for (int i = 0; i < 8; ++i) {
      float4 v = hv[i];
      a0 = fmaf(wh[4*i],   v.x, a0);
      a1 = fmaf(wh[4*i+1], v.y, a1);
      a2 = fmaf(wh[4*i+2], v.z, a2);
      a3 = fmaf(wh[4*i+3], v.w, a3);
    }
    part[q][g] = g0 + ((a0 + a1) + (a2 + a3));
    __syncthreads();
    if (tid < 64) {
      const float gi = part[0][tid]       + part[1][tid];
      const float gf = part[0][64 + tid]  + part[1][64 + tid];
      const float gg = part[0][128 + tid] + part[1][128 + tid];
      const float go = part[0][192 + tid] + part[1][192 + tid];
      c = sigm(gf) * c + sigm(gi) * tanh_(gg);
      const float h = sigm(go) * tanh_(c);
      h_lds[tid] = h;
      hrow[t * 64 + tid] = fmaxf(h, 0.0f);
    }
    __syncthreads();
  }
}

// ---------------- d2: IN=64, H=128, G=512. 512 threads = 512 gates, full dot-192.
__global__ __launch_bounds__(512) void k_d2(
    const float* __restrict__ xin /* [B,T,64] relu'd (in d_ws) */,
    const float* __restrict__ Wih, const float* __restrict__ Whh,
    const float* __restrict__ bih, const float* __restrict__ bhh,
    float* __restrict__ out /* [B,T,128] fp32, no relu */)
{
  const int b   = blockIdx.x;
  const int tid = threadIdx.x;  // == gate row

  __shared__ float h_lds[128];
  __shared__ float xbuf[2][64];
  __shared__ float gsum[512];

  float wx[64];
#pragma unroll
  for (int i = 0; i < 16; ++i) {
    float4 v = *reinterpret_cast<const float4*>(Wih + tid * 64 + i * 4);
    wx[4*i] = v.x; wx[4*i+1] = v.y; wx[4*i+2] = v.z; wx[4*i+3] = v.w;
  }
  float wh[128];
#pragma unroll
  for (int i = 0; i < 32; ++i) {
    float4 v = *reinterpret_cast<const float4*>(Whh + tid * 128 + i * 4);
    wh[4*i] = v.x; wh[4*i+1] = v.y; wh[4*i+2] = v.z; wh[4*i+3] = v.w;
  }
  const float bias = bih[tid] + bhh[tid];

  const float* xrow = xin + (size_t)b * (TT * 64);

  if (tid < 128) h_lds[tid] = 0.0f;
  if (tid < 64) xbuf[0][tid] = xrow[tid];
  float c = 0.0f;
  __syncthreads();

  for (int t = 0; t < TT; ++t) {
    const int cur = t & 1;
    float xn = 0.0f;
    if (tid < 64) {
      const int tn = (t + 1 < TT) ? (t + 1) : t;
      xn = xrow[tn * 64 + tid];
    }
    float a0 = 0.f, a1 = 0.f, a2 = 0.f, a3 = 0.f;
    const float4* xv = reinterpret_cast<const float4*>(&xbuf[cur][0]);
#pragma unroll
    for (int i = 0; i < 16; ++i) {
      float4 v = xv[i];
      a0 = fmaf(wx[4*i],   v.x, a0);
      a1 = fmaf(wx[4*i+1], v.y, a1);
      a2 = fmaf(wx[4*i+2], v.z, a2);
      a3 = fmaf(wx[4*i+3], v.w, a3);
    }
    const float4* hv = reinterpret_cast<const float4*>(&h_lds[0]);
#pragma unroll
    for (int i = 0; i < 32; ++i) {
      float4 v = hv[i];
      a0 = fmaf(wh[4*i],   v.x, a0);
      a1 = fmaf(wh[4*i+1], v.y, a1);
      a2 = fmaf(wh[4*i+2], v.z, a2);
      a3 = fmaf(wh[4*i+3], v.w, a3);
    }
    gsum[tid] = bias + ((a0 + a1) + (a2 + a3));
    if (tid < 64) xbuf[cur ^ 1][tid] = xn;
    __syncthreads();
    if (tid < 128) {
      const float gi = gsum[tid];
      const float gf = gsum[128 + tid];
      const float gg = gsum[256 + tid];
      const float go = gsum[384 + tid];
      c = sigm(gf) * c + sigm(gi) * tanh_(gg);
      const float h = sigm(go) * tanh_(c);
      h_lds[tid] = h;
      out[((size_t)b * TT + t) * 128 + tid] = h;   // FP32 output
    }
    __syncthreads();
  }
}

extern "C" void kernel_launch(void* const* d_in, const int* in_sizes, int n_in,
                              void* d_out, int out_size, void* d_ws, size_t ws_size,
                              hipStream_t stream) {
  const float* x       = (const float*)d_in[0];
  const float* Wih_e1  = (const float*)d_in[1];
  const float* Whh_e1  = (const float*)d_in[2];
  const float* bih_e1  = (const float*)d_in[3];
  const float* bhh_e1  = (const float*)d_in[4];
  const float* Wih_e2  = (const float*)d_in[5];
  const float* Whh_e2  = (const float*)d_in[6];
  const float* bih_e2  = (const float*)d_in[7];
  const float* bhh_e2  = (const float*)d_in[8];
  const float* Wih_d1  = (const float*)d_in[9];
  const float* Whh_d1  = (const float*)d_in[10];
  const float* bih_d1  = (const float*)d_in[11];
  const float* bhh_d1  = (const float*)d_in[12];
  const float* Wih_d2  = (const float*)d_in[13];
  const float* Whh_d2  = (const float*)d_in[14];
  const float* bih_d2  = (const float*)d_in[15];
  const float* bhh_d2  = (const float*)d_in[16];

  // h_e1 parks in d_out's first half (consumed by e2 before d2 overwrites).
  // hd1 (33.5 MB) + lat (16 KB) live in d_ws (round-1 run evidenced the size).
  float* h1  = (float*)d_out;
  float* hd1 = (float*)d_ws;
  float* lat = hd1 + (size_t)BB * TT * 64;
  float* out = (float*)d_out;

  k_e1<<<BB, 512, 0, stream>>>(x, Wih_e1, Whh_e1, bih_e1, bhh_e1, h1);
  k_e2<<<BB, 256, 0, stream>>>(h1, Wih_e2, Whh_e2, bih_e2, bhh_e2, lat);
  k_d1<<<BB, 512, 0, stream>>>(lat, Wih_d1, Whh_d1, bih_d1, bhh_d1, hd1);
  k_d2<<<BB, 512, 0, stream>>>(hd1, Wih_d2, Whh_d2, bih_d2, bhh_d2, out);
}

// Round 4
// 1649.732 us; speedup vs baseline: 1.1350x; 1.1350x over previous
//
#include <hip/hip_runtime.h>

// LSTM autoencoder: B=256, T=512, IN=128, HID=64, LAT=16
// Persistent blocks, 1 block/batch-row (grid=256=#CUs). LDS-broadcast-bound:
// per-CU cost = waves * (K/4) * 12cyc per step. Minimize waves via G=2
// gates/lane (192 weight VGPRs, truly register-resident -> launch_bounds).
//
// Buffers: h1 (fp32 33.5MB) -> d_out first half; hd1+lat -> d_ws (proven size);
// out (fp32 67MB) -> d_out written only by d2.

#define BB 256
#define TT 512

__device__ __forceinline__ float sigm(float v) { return 1.0f / (1.0f + __expf(-v)); }
__device__ __forceinline__ float tanh_(float v) { return 1.0f - 2.0f / (__expf(2.0f * v) + 1.0f); }

#define LD4(dst, off, src)                                   \
  {                                                          \
    float4 _v = *reinterpret_cast<const float4*>(src);       \
    dst[(off)] = _v.x; dst[(off) + 1] = _v.y;                \
    dst[(off) + 2] = _v.z; dst[(off) + 3] = _v.w;            \
  }

// ---------------- e1: IN=128, H=64, gates=256, K=192 ({x128,h64}).
// 256 thr = 2 k-halves x 128 lanes x 2 gates. Weights 2x96 fp32 in regs.
__global__ __launch_bounds__(256, 1) void k_e1(
    const float* __restrict__ x,
    const float* __restrict__ Wih, const float* __restrict__ Whh,
    const float* __restrict__ bih, const float* __restrict__ bhh,
    float* __restrict__ h_out /* [B,T,64] relu'd */)
{
  const int b   = blockIdx.x;
  const int tid = threadIdx.x;
  const int q   = tid >> 7;      // k-half
  const int gp  = tid & 127;
  const int gA  = 2 * gp, gB = gA + 1;

  __shared__ float vh[2][192];   // [0:128)=x(t), [128:192)=h(t-1)
  __shared__ float part[2][256];

  // concat operand vector v[192] = {x[0:128], h[0:64]}
  // half0 = v[0:96]  = x[0:96]            -> Wih cols [0:96)
  // half1 = v[96:192]= {x[96:128], h[0:64]}-> Wih cols[96:128) + Whh cols[0:64)
  float wA[96], wB[96];
  if (q == 0) {
#pragma unroll
    for (int i = 0; i < 24; ++i) {
      LD4(wA, 4 * i, Wih + gA * 128 + 4 * i);
      LD4(wB, 4 * i, Wih + gB * 128 + 4 * i);
    }
  } else {
#pragma unroll
    for (int i = 0; i < 8; ++i) {
      LD4(wA, 4 * i, Wih + gA * 128 + 96 + 4 * i);
      LD4(wB, 4 * i, Wih + gB * 128 + 96 + 4 * i);
    }
#pragma unroll
    for (int i = 0; i < 16; ++i) {
      LD4(wA, 32 + 4 * i, Whh + gA * 64 + 4 * i);
      LD4(wB, 32 + 4 * i, Whh + gB * 64 + 4 * i);
    }
  }
  const float biasA = (q == 0) ? (bih[gA] + bhh[gA]) : 0.0f;
  const float biasB = (q == 0) ? (bih[gB] + bhh[gB]) : 0.0f;

  const float* xrow = x + (size_t)b * (TT * 128);
  float* hrow = h_out + (size_t)b * (TT * 64);

  if (tid < 128) vh[0][tid] = xrow[tid];
  if (tid >= 128 && tid < 192) vh[0][tid] = 0.0f;   // h(-1)=0
  float c = 0.0f;
  __syncthreads();

  int cur = 0;
  for (int t = 0; t < TT; ++t) {
    const int nxt = cur ^ 1;
    float xn = 0.0f;
    if (tid < 128) {
      const int tn = (t + 1 < TT) ? (t + 1) : t;
      xn = xrow[tn * 128 + tid];
    }
    float aA = biasA, aB = biasB;
    const float4* v = reinterpret_cast<const float4*>(&vh[cur][q * 96]);
#pragma unroll
    for (int i = 0; i < 24; ++i) {
      float4 u = v[i];
      aA = fmaf(wA[4*i],   u.x, aA); aB = fmaf(wB[4*i],   u.x, aB);
      aA = fmaf(wA[4*i+1], u.y, aA); aB = fmaf(wB[4*i+1], u.y, aB);
      aA = fmaf(wA[4*i+2], u.z, aA); aB = fmaf(wB[4*i+2], u.z, aB);
      aA = fmaf(wA[4*i+3], u.w, aA); aB = fmaf(wB[4*i+3], u.w, aB);
    }
    *reinterpret_cast<float2*>(&part[q][gA]) = make_float2(aA, aB);
    if (tid < 128) vh[nxt][tid] = xn;
    __syncthreads();
    if (tid < 64) {
      const float gi = part[0][tid]       + part[1][tid];
      const float gf = part[0][64 + tid]  + part[1][64 + tid];
      const float gg = part[0][128 + tid] + part[1][128 + tid];
      const float go = part[0][192 + tid] + part[1][192 + tid];
      c = sigm(gf) * c + sigm(gi) * tanh_(gg);
      const float h = sigm(go) * tanh_(c);
      vh[nxt][128 + tid] = h;
      hrow[t * 64 + tid] = fmaxf(h, 0.0f);
    }
    __syncthreads();
    cur = nxt;
  }
}

// ---------------- e2: IN=64, H=16, gates=64, K=80. ONE wave (64 thr),
// lane = gate. No s_barrier (wave-ordered LDS), so prefetch vm never drains.
__global__ __launch_bounds__(64, 1) void k_e2(
    const float* __restrict__ xin /* [B,T,64] relu'd */,
    const float* __restrict__ Wih, const float* __restrict__ Whh,
    const float* __restrict__ bih, const float* __restrict__ bhh,
    float* __restrict__ lat /* [B,16] relu'd last step */)
{
  const int b   = blockIdx.x;
  const int tid = threadIdx.x;   // gate row

  __shared__ float vh[2][80];    // [0:64)=x(t), [64:80)=h(t-1)
  __shared__ float gs[64];

  float w[80];
#pragma unroll
  for (int i = 0; i < 16; ++i) LD4(w, 4 * i, Wih + tid * 64 + 4 * i);
#pragma unroll
  for (int i = 0; i < 4; ++i)  LD4(w, 64 + 4 * i, Whh + tid * 16 + 4 * i);
  const float bias = bih[tid] + bhh[tid];

  const float* xrow = xin + (size_t)b * (TT * 64);

  vh[0][tid] = xrow[tid];
  if (tid < 16) vh[0][64 + tid] = 0.0f;
  float c = 0.0f;
  __builtin_amdgcn_wave_barrier();

  int cur = 0;
  for (int t = 0; t < TT; ++t) {
    const int nxt = cur ^ 1;
    const int tn = (t + 1 < TT) ? (t + 1) : t;
    const float xn = xrow[tn * 64 + tid];   // deep in flight; no barrier drain
    float a = bias;
    const float4* v = reinterpret_cast<const float4*>(&vh[cur][0]);
#pragma unroll
    for (int i = 0; i < 20; ++i) {
      float4 u = v[i];
      a = fmaf(w[4*i],   u.x, a);
      a = fmaf(w[4*i+1], u.y, a);
      a = fmaf(w[4*i+2], u.z, a);
      a = fmaf(w[4*i+3], u.w, a);
    }
    gs[tid] = a;
    __builtin_amdgcn_wave_barrier();
    if (tid < 16) {
      const float gi = gs[tid];
      const float gf = gs[16 + tid];
      const float gg = gs[32 + tid];
      const float go = gs[48 + tid];
      c = sigm(gf) * c + sigm(gi) * tanh_(gg);
      const float h = sigm(go) * tanh_(c);
      vh[nxt][64 + tid] = h;
      if (t == TT - 1) lat[b * 16 + tid] = fmaxf(h, 0.0f);
    }
    vh[nxt][tid] = xn;
    __builtin_amdgcn_wave_barrier();
    cur = nxt;
  }
}

// ---------------- d1: IN=16 (const latent -> precomputed g0), H=64,
// gates=256, K=64. 128 thr = 2 waves x 2 gates/lane. Weights 2x64 in regs.
__global__ __launch_bounds__(128, 1) void k_d1(
    const float* __restrict__ lat /* [B,16] */,
    const float* __restrict__ Wih, const float* __restrict__ Whh,
    const float* __restrict__ bih, const float* __restrict__ bhh,
    float* __restrict__ h_out /* [B,T,64] relu'd */)
{
  const int b   = blockIdx.x;
  const int tid = threadIdx.x;
  const int gA  = 2 * tid, gB = gA + 1;

  __shared__ float vh[2][64];
  __shared__ float lat_lds[16];
  __shared__ float gsum[256];

  float wA[64], wB[64];
#pragma unroll
  for (int i = 0; i < 16; ++i) {
    LD4(wA, 4 * i, Whh + gA * 64 + 4 * i);
    LD4(wB, 4 * i, Whh + gB * 64 + 4 * i);
  }
  if (tid < 16) lat_lds[tid] = lat[b * 16 + tid];
  if (tid < 64) vh[0][tid] = 0.0f;
  float c = 0.0f;
  __syncthreads();

  float g0A = bih[gA] + bhh[gA];
  float g0B = bih[gB] + bhh[gB];
#pragma unroll
  for (int i = 0; i < 16; ++i) {
    g0A = fmaf(Wih[gA * 16 + i], lat_lds[i], g0A);
    g0B = fmaf(Wih[gB * 16 + i], lat_lds[i], g0B);
  }

  float* hrow = h_out + (size_t)b * (TT * 64);

  int cur = 0;
  for (int t = 0; t < TT; ++t) {
    const int nxt = cur ^ 1;
    float aA = g0A, aB = g0B;
    const float4* v = reinterpret_cast<const float4*>(&vh[cur][0]);
#pragma unroll
    for (int i = 0; i < 16; ++i) {
      float4 u = v[i];
      aA = fmaf(wA[4*i],   u.x, aA); aB = fmaf(wB[4*i],   u.x, aB);
      aA = fmaf(wA[4*i+1], u.y, aA); aB = fmaf(wB[4*i+1], u.y, aB);
      aA = fmaf(wA[4*i+2], u.z, aA); aB = fmaf(wB[4*i+2], u.z, aB);
      aA = fmaf(wA[4*i+3], u.w, aA); aB = fmaf(wB[4*i+3], u.w, aB);
    }
    *reinterpret_cast<float2*>(&gsum[gA]) = make_float2(aA, aB);
    __syncthreads();
    if (tid < 64) {
      const float gi = gsum[tid];
      const float gf = gsum[64 + tid];
      const float gg = gsum[128 + tid];
      const float go = gsum[192 + tid];
      c = sigm(gf) * c + sigm(gi) * tanh_(gg);
      const float h = sigm(go) * tanh_(c);
      vh[nxt][tid] = h;
      hrow[t * 64 + tid] = fmaxf(h, 0.0f);
    }
    __syncthreads();
    cur = nxt;
  }
}

// ---------------- d2: IN=64, H=128, gates=512, K=192 ({x64,h128}).
// 512 thr = 2 k-halves x 256 lanes x 2 gates. Weights 2x96 fp32 in regs.
// launch_bounds(512,2): 2 waves/SIMD -> 256-VGPR budget, weights resident.
__global__ __launch_bounds__(512, 2) void k_d2(
    const float* __restrict__ xin /* [B,T,64] relu'd (d_ws) */,
    const float* __restrict__ Wih, const float* __restrict__ Whh,
    const float* __restrict__ bih, const float* __restrict__ bhh,
    float* __restrict__ out /* [B,T,128] fp32, no relu */)
{
  const int b   = blockIdx.x;
  const int tid = threadIdx.x;
  const int q   = tid >> 8;      // k-half
  const int gp  = tid & 255;
  const int gA  = 2 * gp, gB = gA + 1;

  __shared__ float vh[2][192];   // [0:64)=x(t), [64:192)=h(t-1)
  __shared__ float part[2][512];

  // concat v[192] = {x[0:64], h[0:128]}
  // half0 = {x[0:64], h[0:32]}  -> Wih cols[0:64) + Whh cols[0:32)
  // half1 = h[32:128]           -> Whh cols[32:128)
  float wA[96], wB[96];
  if (q == 0) {
#pragma unroll
    for (int i = 0; i < 16; ++i) {
      LD4(wA, 4 * i, Wih + gA * 64 + 4 * i);
      LD4(wB, 4 * i, Wih + gB * 64 + 4 * i);
    }
#pragma unroll
    for (int i = 0; i < 8; ++i) {
      LD4(wA, 64 + 4 * i, Whh + gA * 128 + 4 * i);
      LD4(wB, 64 + 4 * i, Whh + gB * 128 + 4 * i);
    }
  } else {
#pragma unroll
    for (int i = 0; i < 24; ++i) {
      LD4(wA, 4 * i, Whh + gA * 128 + 32 + 4 * i);
      LD4(wB, 4 * i, Whh + gB * 128 + 32 + 4 * i);
    }
  }
  const float biasA = (q == 0) ? (bih[gA] + bhh[gA]) : 0.0f;
  const float biasB = (q == 0) ? (bih[gB] + bhh[gB]) : 0.0f;

  const float* xrow = xin + (size_t)b * (TT * 64);

  if (tid < 64) vh[0][tid] = xrow[tid];
  if (tid >= 64 && tid < 192) vh[0][tid] = 0.0f;   // h(-1)=0
  float c = 0.0f;
  __syncthreads();

  int cur = 0;
  for (int t = 0; t < TT; ++t) {
    const int nxt = cur ^ 1;
    float xn = 0.0f;
    if (tid < 64) {
      const int tn = (t + 1 < TT) ? (t + 1) : t;
      xn = xrow[tn * 64 + tid];
    }
    float aA = biasA, aB = biasB;
    const float4* v = reinterpret_cast<const float4*>(&vh[cur][q * 96]);
#pragma unroll
    for (int i = 0; i < 24; ++i) {
      float4 u = v[i];
      aA = fmaf(wA[4*i],   u.x, aA); aB = fmaf(wB[4*i],   u.x, aB);
      aA = fmaf(wA[4*i+1], u.y, aA); aB = fmaf(wB[4*i+1], u.y, aB);
      aA = fmaf(wA[4*i+2], u.z, aA); aB = fmaf(wB[4*i+2], u.z, aB);
      aA = fmaf(wA[4*i+3], u.w, aA); aB = fmaf(wB[4*i+3], u.w, aB);
    }
    *reinterpret_cast<float2*>(&part[q][gA]) = make_float2(aA, aB);
    if (tid < 64) vh[nxt][tid] = xn;
    __syncthreads();
    if (tid < 128) {
      const float gi = part[0][tid]       + part[1][tid];
      const float gf = part[0][128 + tid] + part[1][128 + tid];
      const float gg = part[0][256 + tid] + part[1][256 + tid];
      const float go = part[0][384 + tid] + part[1][384 + tid];
      c = sigm(gf) * c + sigm(gi) * tanh_(gg);
      const float h = sigm(go) * tanh_(c);
      vh[nxt][64 + tid] = h;
      out[((size_t)b * TT + t) * 128 + tid] = h;
    }
    __syncthreads();
    cur = nxt;
  }
}

extern "C" void kernel_launch(void* const* d_in, const int* in_sizes, int n_in,
                              void* d_out, int out_size, void* d_ws, size_t ws_size,
                              hipStream_t stream) {
  const float* x       = (const float*)d_in[0];
  const float* Wih_e1  = (const float*)d_in[1];
  const float* Whh_e1  = (const float*)d_in[2];
  const float* bih_e1  = (const float*)d_in[3];
  const float* bhh_e1  = (const float*)d_in[4];
  const float* Wih_e2  = (const float*)d_in[5];
  const float* Whh_e2  = (const float*)d_in[6];
  const float* bih_e2  = (const float*)d_in[7];
  const float* bhh_e2  = (const float*)d_in[8];
  const float* Wih_d1  = (const float*)d_in[9];
  const float* Whh_d1  = (const float*)d_in[10];
  const float* bih_d1  = (const float*)d_in[11];
  const float* bhh_d1  = (const float*)d_in[12];
  const float* Wih_d2  = (const float*)d_in[13];
  const float* Whh_d2  = (const float*)d_in[14];
  const float* bih_d2  = (const float*)d_in[15];
  const float* bhh_d2  = (const float*)d_in[16];

  float* h1  = (float*)d_out;          // e1 out / e2 in (d_out first half)
  float* hd1 = (float*)d_ws;           // d1 out / d2 in
  float* lat = hd1 + (size_t)BB * TT * 64;
  float* out = (float*)d_out;

  k_e1<<<BB, 256, 0, stream>>>(x, Wih_e1, Whh_e1, bih_e1, bhh_e1, h1);
  k_e2<<<BB, 64, 0, stream>>>(h1, Wih_e2, Whh_e2, bih_e2, bhh_e2, lat);
  k_d1<<<BB, 128, 0, stream>>>(lat, Wih_d1, Whh_d1, bih_d1, bhh_d1, hd1);
  k_d2<<<BB, 512, 0, stream>>>(hd1, Wih_d2, Whh_d2, bih_d2, bhh_d2, out);
}

// Round 5
// 1425.016 us; speedup vs baseline: 1.3139x; 1.1577x over previous
//
#include <hip/hip_runtime.h>

// LSTM autoencoder: B=256, T=512, IN=128, HID=64, LAT=16
// Persistent blocks, 1 block/batch-row. Per-step cost model (per CU):
//   LDS broadcast = (#ds_read_b128 instrs) * 12 cyc  [the binding pipe]
//   VALU = wave-instrs / 2
// f16x2 weights+operands + v_dot2_f32_f16 (f32 accum):
//   - halves LDS instrs per value, 2 MAC/VALU-instr
//   - weight regs halve -> G=4 gates/lane fits in <=96 dwords (no spill;
//     fp32 weights at 192 regs spilled in rounds 3/4: WRITE_SIZE showed
//     +69MB scratch write-backs)
// K-split Q=4 partials reduced in-wave via DPP quad_perm (VALU, not LDS).
// e2 stays fp32 single-wave (proven, small).
//
// Buffers: h1 f32 -> d_out first half (e2 consumes before d2 overwrites);
// hd1 f32 + lat -> d_ws (layout proven in round 3); out f32 -> d_out.

#define BB 256
#define TT 512

typedef _Float16 f16x2 __attribute__((ext_vector_type(2)));

__device__ __forceinline__ float sigm(float v) { return 1.0f / (1.0f + __expf(-v)); }
__device__ __forceinline__ float tanh_(float v) { return 1.0f - 2.0f / (__expf(2.0f * v) + 1.0f); }

__device__ __forceinline__ float dot2(f16x2 a, f16x2 b, float c) {
#if __has_builtin(__builtin_amdgcn_fdot2)
  return __builtin_amdgcn_fdot2(a, b, c, false);
#else
  float d = c;
  asm("v_dot2_f32_f16 %0, %1, %2, %0" : "+v"(d) : "v"(a), "v"(b));
  return d;
#endif
}

// quad_perm xor1 (0xB1) / xor2 (0x4E) add-reduction within lane-quads
__device__ __forceinline__ float qsum1(float v) {
  int t = __builtin_amdgcn_update_dpp(0, __float_as_int(v), 0xB1, 0xF, 0xF, true);
  return v + __int_as_float(t);
}
__device__ __forceinline__ float qsum2(float v) {
  int t = __builtin_amdgcn_update_dpp(0, __float_as_int(v), 0x4E, 0xF, 0xF, true);
  return v + __int_as_float(t);
}

__device__ __forceinline__ unsigned packh2(float lo, float hi) {
  f16x2 p; p.x = (_Float16)lo; p.y = (_Float16)hi;   // RNE converts
  return __builtin_bit_cast(unsigned, p);
}
__device__ __forceinline__ f16x2 ash2(unsigned u) {
  return __builtin_bit_cast(f16x2, u);
}

// ---------------- e1: IN=128, H=64, gates=256, K=192 ({x128,h64}).
// 256 thr: lane=(gc,q), q=tid&3 k-slice, gc=tid>>2 owns gates 4gc..4gc+3.
__global__ __launch_bounds__(256, 1) void k_e1(
    const float* __restrict__ x,
    const float* __restrict__ Wih, const float* __restrict__ Whh,
    const float* __restrict__ bih, const float* __restrict__ bhh,
    float* __restrict__ h_out /* [B,T,64] relu'd */)
{
  const int b = blockIdx.x, tid = threadIdx.x;
  const int q = tid & 3, gc = tid >> 2;
  const int g0 = gc * 4;

  __shared__ unsigned vh2[2][96];   // dwords: x -> [0,64), h -> [64,96)
  __shared__ float gsum[256];

  f16x2 w2[4][24];
  float bias[4];
#pragma unroll
  for (int g = 0; g < 4; ++g) {
    const int gg = g0 + g;
    bias[g] = (q == 0) ? (bih[gg] + bhh[gg]) : 0.0f;
#pragma unroll
    for (int j = 0; j < 24; ++j) {
      const int k0 = q * 48 + 2 * j;
      float a, bb;
      if (k0 < 128) a = Wih[gg * 128 + k0]; else a = Whh[gg * 64 + (k0 - 128)];
      if (k0 + 1 < 128) bb = Wih[gg * 128 + k0 + 1]; else bb = Whh[gg * 64 + (k0 + 1 - 128)];
      f16x2 p; p.x = (_Float16)a; p.y = (_Float16)bb;
      w2[g][j] = p;
    }
  }

  const float* xrow = x + (size_t)b * (TT * 128);
  float* hrow = h_out + (size_t)b * (TT * 64);

  if (tid < 128) {
    float v = xrow[tid];
    float vhi = __shfl_down(v, 1);
    if ((tid & 1) == 0) vh2[0][tid >> 1] = packh2(v, vhi);
  }
  if (tid >= 128 && tid < 160) vh2[0][64 + (tid - 128)] = 0u;  // h(-1)=0
  float c = 0.0f;
  __syncthreads();

  int cur = 0;
  for (int t = 0; t < TT; ++t) {
    const int nxt = cur ^ 1;
    float xn = 0.0f;
    if (tid < 128) {
      const int tn = (t + 1 < TT) ? (t + 1) : t;
      xn = xrow[tn * 128 + tid];
    }
    float a0 = bias[0], a1 = bias[1], a2 = bias[2], a3 = bias[3];
    const uint4* vp = reinterpret_cast<const uint4*>(&vh2[cur][q * 24]);
#pragma unroll
    for (int i = 0; i < 6; ++i) {
      uint4 u = vp[i];
      const f16x2 o0 = ash2(u.x), o1 = ash2(u.y), o2 = ash2(u.z), o3 = ash2(u.w);
      a0 = dot2(w2[0][4*i+0], o0, a0); a1 = dot2(w2[1][4*i+0], o0, a1);
      a2 = dot2(w2[2][4*i+0], o0, a2); a3 = dot2(w2[3][4*i+0], o0, a3);
      a0 = dot2(w2[0][4*i+1], o1, a0); a1 = dot2(w2[1][4*i+1], o1, a1);
      a2 = dot2(w2[2][4*i+1], o1, a2); a3 = dot2(w2[3][4*i+1], o1, a3);
      a0 = dot2(w2[0][4*i+2], o2, a0); a1 = dot2(w2[1][4*i+2], o2, a1);
      a2 = dot2(w2[2][4*i+2], o2, a2); a3 = dot2(w2[3][4*i+2], o2, a3);
      a0 = dot2(w2[0][4*i+3], o3, a0); a1 = dot2(w2[1][4*i+3], o3, a1);
      a2 = dot2(w2[2][4*i+3], o3, a2); a3 = dot2(w2[3][4*i+3], o3, a3);
    }
    a0 = qsum2(qsum1(a0)); a1 = qsum2(qsum1(a1));
    a2 = qsum2(qsum1(a2)); a3 = qsum2(qsum1(a3));
    if (q == 0) *reinterpret_cast<float4*>(&gsum[g0]) = make_float4(a0, a1, a2, a3);
    if (tid < 128) {  // pack x(t+1) into nxt (nxt not read this step)
      float vhi = __shfl_down(xn, 1);
      if ((tid & 1) == 0) vh2[nxt][tid >> 1] = packh2(xn, vhi);
    }
    __syncthreads();
    if (tid < 64) {
      const float gi = gsum[tid], gf = gsum[64 + tid];
      const float gg = gsum[128 + tid], go = gsum[192 + tid];
      c = sigm(gf) * c + sigm(gi) * tanh_(gg);
      const float h = sigm(go) * tanh_(c);
      const float hhi = __shfl_down(h, 1);
      if ((tid & 1) == 0) vh2[nxt][64 + (tid >> 1)] = packh2(h, hhi);
      hrow[t * 64 + tid] = fmaxf(h, 0.0f);
    }
    __syncthreads();
    cur = nxt;
  }
}

// ---------------- e2: IN=64, H=16, gates=64, K=80. ONE wave, fp32
// (unchanged from round 4 — proven correct, small cost, zero risk).
__global__ __launch_bounds__(64, 1) void k_e2(
    const float* __restrict__ xin,
    const float* __restrict__ Wih, const float* __restrict__ Whh,
    const float* __restrict__ bih, const float* __restrict__ bhh,
    float* __restrict__ lat /* [B,16] relu'd last step */)
{
  const int b = blockIdx.x, tid = threadIdx.x;

  __shared__ float vh[2][80];
  __shared__ float gs[64];

  float w[80];
#pragma unroll
  for (int i = 0; i < 16; ++i) {
    float4 v = *reinterpret_cast<const float4*>(Wih + tid * 64 + 4 * i);
    w[4*i] = v.x; w[4*i+1] = v.y; w[4*i+2] = v.z; w[4*i+3] = v.w;
  }
#pragma unroll
  for (int i = 0; i < 4; ++i) {
    float4 v = *reinterpret_cast<const float4*>(Whh + tid * 16 + 4 * i);
    w[64+4*i] = v.x; w[64+4*i+1] = v.y; w[64+4*i+2] = v.z; w[64+4*i+3] = v.w;
  }
  const float bias = bih[tid] + bhh[tid];

  const float* xrow = xin + (size_t)b * (TT * 64);

  vh[0][tid] = xrow[tid];
  if (tid < 16) vh[0][64 + tid] = 0.0f;
  float c = 0.0f;
  __builtin_amdgcn_wave_barrier();

  int cur = 0;
  for (int t = 0; t < TT; ++t) {
    const int nxt = cur ^ 1;
    const int tn = (t + 1 < TT) ? (t + 1) : t;
    const float xn = xrow[tn * 64 + tid];
    float a = bias;
    const float4* v = reinterpret_cast<const float4*>(&vh[cur][0]);
#pragma unroll
    for (int i = 0; i < 20; ++i) {
      float4 u = v[i];
      a = fmaf(w[4*i],   u.x, a);
      a = fmaf(w[4*i+1], u.y, a);
      a = fmaf(w[4*i+2], u.z, a);
      a = fmaf(w[4*i+3], u.w, a);
    }
    gs[tid] = a;
    __builtin_amdgcn_wave_barrier();
    if (tid < 16) {
      const float gi = gs[tid], gf = gs[16 + tid];
      const float gg = gs[32 + tid], go = gs[48 + tid];
      c = sigm(gf) * c + sigm(gi) * tanh_(gg);
      const float h = sigm(go) * tanh_(c);
      vh[nxt][64 + tid] = h;
      if (t == TT - 1) lat[b * 16 + tid] = fmaxf(h, 0.0f);
    }
    vh[nxt][tid] = xn;
    __builtin_amdgcn_wave_barrier();
    cur = nxt;
  }
}

// ---------------- d1: IN=16 (const latent -> precomputed proj), H=64,
// gates=256, K=64 (h only). 128 thr: q=tid&1 k-half, gc=tid>>1, 4 gates/lane.
__global__ __launch_bounds__(128, 1) void k_d1(
    const float* __restrict__ lat,
    const float* __restrict__ Wih, const float* __restrict__ Whh,
    const float* __restrict__ bih, const float* __restrict__ bhh,
    float* __restrict__ h_out /* [B,T,64] relu'd */)
{
  const int b = blockIdx.x, tid = threadIdx.x;
  const int q = tid & 1, gc = tid >> 1;
  const int g0 = gc * 4;

  __shared__ unsigned vh2[2][32];   // h as f16x2
  __shared__ float lat_lds[16];
  __shared__ float gsum[256];

  f16x2 w2[4][16];
#pragma unroll
  for (int g = 0; g < 4; ++g) {
    const int gg = g0 + g;
#pragma unroll
    for (int j = 0; j < 16; ++j) {
      const int k0 = q * 32 + 2 * j;
      f16x2 p; p.x = (_Float16)Whh[gg * 64 + k0]; p.y = (_Float16)Whh[gg * 64 + k0 + 1];
      w2[g][j] = p;
    }
  }
  if (tid < 16) lat_lds[tid] = lat[b * 16 + tid];
  if (tid < 32) vh2[0][tid] = 0u;
  float c = 0.0f;
  __syncthreads();

  float g0p[4] = {0.f, 0.f, 0.f, 0.f};
  if (q == 0) {
#pragma unroll
    for (int g = 0; g < 4; ++g) {
      const int gg = g0 + g;
      float a = bih[gg] + bhh[gg];
#pragma unroll
      for (int i = 0; i < 16; ++i) a = fmaf(Wih[gg * 16 + i], lat_lds[i], a);
      g0p[g] = a;
    }
  }

  float* hrow = h_out + (size_t)b * (TT * 64);

  int cur = 0;
  for (int t = 0; t < TT; ++t) {
    const int nxt = cur ^ 1;
    float a0 = g0p[0], a1 = g0p[1], a2 = g0p[2], a3 = g0p[3];
    const uint4* vp = reinterpret_cast<const uint4*>(&vh2[cur][q * 16]);
#pragma unroll
    for (int i = 0; i < 4; ++i) {
      uint4 u = vp[i];
      const f16x2 o0 = ash2(u.x), o1 = ash2(u.y), o2 = ash2(u.z), o3 = ash2(u.w);
      a0 = dot2(w2[0][4*i+0], o0, a0); a1 = dot2(w2[1][4*i+0], o0, a1);
      a2 = dot2(w2[2][4*i+0], o0, a2); a3 = dot2(w2[3][4*i+0], o0, a3);
      a0 = dot2(w2[0][4*i+1], o1, a0); a1 = dot2(w2[1][4*i+1], o1, a1);
      a2 = dot2(w2[2][4*i+1], o1, a2); a3 = dot2(w2[3][4*i+1], o1, a3);
      a0 = dot2(w2[0][4*i+2], o2, a0); a1 = dot2(w2[1][4*i+2], o2, a1);
      a2 = dot2(w2[2][4*i+2], o2, a2); a3 = dot2(w2[3][4*i+2], o2, a3);
      a0 = dot2(w2[0][4*i+3], o3, a0); a1 = dot2(w2[1][4*i+3], o3, a1);
      a2 = dot2(w2[2][4*i+3], o3, a2); a3 = dot2(w2[3][4*i+3], o3, a3);
    }
    // pair-reduce (q0,q1 are lane neighbors): one xor1 stage
    a0 = qsum1(a0); a1 = qsum1(a1); a2 = qsum1(a2); a3 = qsum1(a3);
    if (q == 0) *reinterpret_cast<float4*>(&gsum[g0]) = make_float4(a0, a1, a2, a3);
    __syncthreads();
    if (tid < 64) {
      const float gi = gsum[tid], gf = gsum[64 + tid];
      const float gg = gsum[128 + tid], go = gsum[192 + tid];
      c = sigm(gf) * c + sigm(gi) * tanh_(gg);
      const float h = sigm(go) * tanh_(c);
      const float hhi = __shfl_down(h, 1);
      if ((tid & 1) == 0) vh2[nxt][tid >> 1] = packh2(h, hhi);
      hrow[t * 64 + tid] = fmaxf(h, 0.0f);
    }
    __syncthreads();
    cur = nxt;
  }
}

// ---------------- d2: IN=64, H=128, gates=512, K=192 ({x64,h128}).
// 512 thr: q=tid&3, gc=tid>>2 in [0,128), 4 gates/lane.
__global__ __launch_bounds__(512, 2) void k_d2(
    const float* __restrict__ xin /* [B,T,64] (d_ws) */,
    const float* __restrict__ Wih, const float* __restrict__ Whh,
    const float* __restrict__ bih, const float* __restrict__ bhh,
    float* __restrict__ out /* [B,T,128] fp32, no relu */)
{
  const int b = blockIdx.x, tid = threadIdx.x;
  const int q = tid & 3, gc = tid >> 2;
  const int g0 = gc * 4;

  __shared__ unsigned vh2[2][96];   // dwords: x -> [0,32), h -> [32,96)
  __shared__ float gsum[512];

  f16x2 w2[4][24];
  float bias[4];
#pragma unroll
  for (int g = 0; g < 4; ++g) {
    const int gg = g0 + g;
    bias[g] = (q == 0) ? (bih[gg] + bhh[gg]) : 0.0f;
#pragma unroll
    for (int j = 0; j < 24; ++j) {
      const int k0 = q * 48 + 2 * j;
      float a, bb;
      if (k0 < 64) a = Wih[gg * 64 + k0]; else a = Whh[gg * 128 + (k0 - 64)];
      if (k0 + 1 < 64) bb = Wih[gg * 64 + k0 + 1]; else bb = Whh[gg * 128 + (k0 + 1 - 64)];
      f16x2 p; p.x = (_Float16)a; p.y = (_Float16)bb;
      w2[g][j] = p;
    }
  }

  const float* xrow = xin + (size_t)b * (TT * 64);

  if (tid < 64) {
    float v = xrow[tid];
    float vhi = __shfl_down(v, 1);
    if ((tid & 1) == 0) vh2[0][tid >> 1] = packh2(v, vhi);
  }
  if (tid >= 64 && tid < 128) vh2[0][32 + (tid - 64)] = 0u;  // h(-1)=0
  float c = 0.0f;
  __syncthreads();

  int cur = 0;
  for (int t = 0; t < TT; ++t) {
    const int nxt = cur ^ 1;
    float xn = 0.0f;
    if (tid < 64) {
      const int tn = (t + 1 < TT) ? (t + 1) : t;
      xn = xrow[tn * 64 + tid];
    }
    float a0 = bias[0], a1 = bias[1], a2 = bias[2], a3 = bias[3];
    const uint4* vp = reinterpret_cast<const uint4*>(&vh2[cur][q * 24]);
#pragma unroll
    for (int i = 0; i < 6; ++i) {
      uint4 u = vp[i];
      const f16x2 o0 = ash2(u.x), o1 = ash2(u.y), o2 = ash2(u.z), o3 = ash2(u.w);
      a0 = dot2(w2[0][4*i+0], o0, a0); a1 = dot2(w2[1][4*i+0], o0, a1);
      a2 = dot2(w2[2][4*i+0], o0, a2); a3 = dot2(w2[3][4*i+0], o0, a3);
      a0 = dot2(w2[0][4*i+1], o1, a0); a1 = dot2(w2[1][4*i+1], o1, a1);
      a2 = dot2(w2[2][4*i+1], o1, a2); a3 = dot2(w2[3][4*i+1], o1, a3);
      a0 = dot2(w2[0][4*i+2], o2, a0); a1 = dot2(w2[1][4*i+2], o2, a1);
      a2 = dot2(w2[2][4*i+2], o2, a2); a3 = dot2(w2[3][4*i+2], o2, a3);
      a0 = dot2(w2[0][4*i+3], o3, a0); a1 = dot2(w2[1][4*i+3], o3, a1);
      a2 = dot2(w2[2][4*i+3], o3, a2); a3 = dot2(w2[3][4*i+3], o3, a3);
    }
    a0 = qsum2(qsum1(a0)); a1 = qsum2(qsum1(a1));
    a2 = qsum2(qsum1(a2)); a3 = qsum2(qsum1(a3));
    if (q == 0) *reinterpret_cast<float4*>(&gsum[g0]) = make_float4(a0, a1, a2, a3);
    if (tid < 64) {
      float vhi = __shfl_down(xn, 1);
      if ((tid & 1) == 0) vh2[nxt][tid >> 1] = packh2(xn, vhi);
    }
    __syncthreads();
    if (tid < 128) {
      const float gi = gsum[tid], gf = gsum[128 + tid];
      const float gg = gsum[256 + tid], go = gsum[384 + tid];
      c = sigm(gf) * c + sigm(gi) * tanh_(gg);
      const float h = sigm(go) * tanh_(c);
      const float hhi = __shfl_down(h, 1);
      if ((tid & 1) == 0) vh2[nxt][32 + (tid >> 1)] = packh2(h, hhi);
      out[((size_t)b * TT + t) * 128 + tid] = h;
    }
    __syncthreads();
    cur = nxt;
  }
}

extern "C" void kernel_launch(void* const* d_in, const int* in_sizes, int n_in,
                              void* d_out, int out_size, void* d_ws, size_t ws_size,
                              hipStream_t stream) {
  const float* x       = (const float*)d_in[0];
  const float* Wih_e1  = (const float*)d_in[1];
  const float* Whh_e1  = (const float*)d_in[2];
  const float* bih_e1  = (const float*)d_in[3];
  const float* bhh_e1  = (const float*)d_in[4];
  const float* Wih_e2  = (const float*)d_in[5];
  const float* Whh_e2  = (const float*)d_in[6];
  const float* bih_e2  = (const float*)d_in[7];
  const float* bhh_e2  = (const float*)d_in[8];
  const float* Wih_d1  = (const float*)d_in[9];
  const float* Whh_d1  = (const float*)d_in[10];
  const float* bih_d1  = (const float*)d_in[11];
  const float* bhh_d1  = (const float*)d_in[12];
  const float* Wih_d2  = (const float*)d_in[13];
  const float* Whh_d2  = (const float*)d_in[14];
  const float* bih_d2  = (const float*)d_in[15];
  const float* bhh_d2  = (const float*)d_in[16];

  float* h1  = (float*)d_out;          // e1 out / e2 in (d_out first half)
  float* hd1 = (float*)d_ws;           // d1 out / d2 in
  float* lat = hd1 + (size_t)BB * TT * 64;
  float* out = (float*)d_out;

  k_e1<<<BB, 256, 0, stream>>>(x, Wih_e1, Whh_e1, bih_e1, bhh_e1, h1);
  k_e2<<<BB, 64, 0, stream>>>(h1, Wih_e2, Whh_e2, bih_e2, bhh_e2, lat);
  k_d1<<<BB, 128, 0, stream>>>(lat, Wih_d1, Whh_d1, bih_d1, bhh_d1, hd1);
  k_d2<<<BB, 512, 0, stream>>>(hd1, Wih_d2, Whh_d2, bih_d2, bhh_d2, out);
}

// Round 6
// 1145.515 us; speedup vs baseline: 1.6345x; 1.2440x over previous
//
#include <hip/hip_runtime.h>

// LSTM autoencoder, fully fused single kernel. B=256 blocks (1/CU), 512 thr.
// All layers row-local => no inter-block deps. Two lag-1 pipelines:
//   e-loop: e1 (all 512 lanes) || e2 (16 lanes in each of waves 0-3, lag 1)
//   d-loop: d2 (all 512 lanes) || d1 (waves 0-3, lag 1 ahead of d2)
// Quad-owns-unit mapping: lanes (4j..4j+3) = k-slices q of unit j's 4 gates
// {j,H+j,2H+j,3H+j}; DPP quad-reduce -> every lane holds all 4 gate preacts
// -> c/h update in-register (redundant x4) -> ds_write_b16 h. ONE barrier/step.
// f16x2 weights in regs + v_dot2_f32_f16 (f32 accum). h/x operands f16 in LDS.
// x: depth-2 register prefetch on wave 7. Intermediates never touch HBM.

#define BB 256
#define TT 512

typedef _Float16 half2v __attribute__((ext_vector_type(2)));

static __device__ __forceinline__ float sigm(float v){ return 1.0f/(1.0f+__expf(-v)); }
static __device__ __forceinline__ float tanh_(float v){ return 1.0f - 2.0f/(__expf(2.0f*v)+1.0f); }
static __device__ __forceinline__ float dot2(half2v a, half2v b, float c){
  return __builtin_amdgcn_fdot2(a,b,c,false);
}
static __device__ __forceinline__ float qsum1(float v){
  int t = __builtin_amdgcn_update_dpp(0, __float_as_int(v), 0xB1, 0xF, 0xF, true);
  return v + __int_as_float(t);
}
static __device__ __forceinline__ float qsum2(float v){
  int t = __builtin_amdgcn_update_dpp(0, __float_as_int(v), 0x4E, 0xF, 0xF, true);
  return v + __int_as_float(t);
}
static __device__ __forceinline__ unsigned packh2(float lo, float hi){
  half2v p; p.x=(_Float16)lo; p.y=(_Float16)hi;
  return __builtin_bit_cast(unsigned, p);
}
static __device__ __forceinline__ half2v ash2(unsigned u){ return __builtin_bit_cast(half2v,u); }
static __device__ __forceinline__ half2v mkh2(float lo, float hi){
  half2v p; p.x=(_Float16)lo; p.y=(_Float16)hi; return p;
}

__global__ void __launch_bounds__(512) k_fused(
    const float* __restrict__ x,
    const float* __restrict__ WihE1, const float* __restrict__ WhhE1,
    const float* __restrict__ bihE1, const float* __restrict__ bhhE1,
    const float* __restrict__ WihE2, const float* __restrict__ WhhE2,
    const float* __restrict__ bihE2, const float* __restrict__ bhhE2,
    const float* __restrict__ WihD1, const float* __restrict__ WhhD1,
    const float* __restrict__ bihD1, const float* __restrict__ bhhD1,
    const float* __restrict__ WihD2, const float* __restrict__ WhhD2,
    const float* __restrict__ bihD2, const float* __restrict__ bhhD2,
    float* __restrict__ out)
{
  const int b = blockIdx.x, tid = threadIdx.x;

  __shared__ unsigned vhE [2*96];   // e1 operand: x 64dw + h 32dw (f16)
  __shared__ unsigned vhE2[2*16];   // e2 h (8dw) + zero pad (8dw)
  __shared__ unsigned rngE[2*32];   // relu(h_e1) ring, 64 f16/row
  __shared__ unsigned vhD1[2*32];   // d1 h
  __shared__ unsigned vhD2[2*64];   // d2 h (128 f16)
  __shared__ unsigned rngD[2*32];   // relu(h_d1) ring
  __shared__ float    latF[16];

  //======================= ENCODER: e1 || e2 (lag 1) =======================
  {
    // e1 role (all 512): q1 in [0,8), unit j1 in [0,64); rows {j1,64+j1,128+j1,192+j1}
    const int q1 = tid & 7, j1 = tid >> 3;
    half2v w1[4][12];
    float bias1[4];
#pragma unroll
    for (int g=0; g<4; ++g){
      const int row = g*64 + j1;
      bias1[g] = (q1==0) ? (bihE1[row]+bhhE1[row]) : 0.0f;
#pragma unroll
      for (int m=0;m<12;++m){
        const int k0 = 24*q1 + 2*m;    // concat {x:128, h:64}
        const float lo = (k0   < 128)? WihE1[row*128+k0]   : WhhE1[row*64 + (k0-128)];
        const float hi = (k0+1 < 128)? WihE1[row*128+k0+1] : WhhE1[row*64 + (k0+1-128)];
        w1[g][m] = mkh2(lo,hi);
      }
    }
    // e2 role: first 16 lanes of waves 0..3 (one per SIMD). unit j2 in [0,16)
    const int lw = tid & 63, wv = tid >> 6;
    const bool e2act = (wv < 4) && (lw < 16);
    const int q2 = lw & 3;
    const int j2 = wv*4 + (lw >> 2);
    half2v w2[4][12];
    float bias2[4];
    if (e2act){
#pragma unroll
      for (int g=0; g<4; ++g){
        const int row = g*16 + j2;
        bias2[g] = (q2==0) ? (bihE2[row]+bhhE2[row]) : 0.0f;
#pragma unroll
        for (int m=0;m<12;++m){
          const int k0 = 24*q2 + 2*m;  // concat {h1:64, h:16, pad:16}
          float lo = 0.0f, hi = 0.0f;
          if (k0 < 64)        lo = WihE2[row*64+k0];
          else if (k0 < 80)   lo = WhhE2[row*16 + (k0-64)];
          if (k0+1 < 64)      hi = WihE2[row*64+k0+1];
          else if (k0+1 < 80) hi = WhhE2[row*16 + (k0+1-64)];
          w2[g][m] = mkh2(lo,hi);
        }
      }
    }
    // x staging role: wave 7, depth-2 prefetch
    const bool xact = (tid >= 448);
    const int  xl   = tid - 448;
    const float* xrow = x + (size_t)b * (TT*128);
    float2 xa, xb;
    if (xact){
      float2 v0 = *(const float2*)(xrow + 2*xl);
      vhE[xl] = packh2(v0.x, v0.y);            // x(0) -> parity 0
      xa = *(const float2*)(xrow + 1*128 + 2*xl);
      xb = *(const float2*)(xrow + 2*128 + 2*xl);
    }
    if (tid >= 64 && tid < 96)  vhE[64 + (tid-64)] = 0u;   // e1 h(-1)=0
    if (tid >= 96 && tid < 128) vhE2[tid-96] = 0u;         // e2 h + pads = 0 (both parities)
    float c1 = 0.0f, c2 = 0.0f;
    __syncthreads();

    for (int t = 0; t <= TT; ++t){
      const int cur = t & 1, nxt = cur ^ 1;
      // ----- e1 step t
      if (t < TT){
        float a[4] = {bias1[0], bias1[1], bias1[2], bias1[3]};
        const uint4* vp = (const uint4*)(vhE + cur*96 + q1*12);
#pragma unroll
        for (int r=0;r<3;++r){
          const uint4 u = vp[r];
          const half2v o0=ash2(u.x), o1=ash2(u.y), o2=ash2(u.z), o3=ash2(u.w);
#pragma unroll
          for (int g=0; g<4; ++g){
            a[g] = dot2(w1[g][4*r+0], o0, a[g]);
            a[g] = dot2(w1[g][4*r+1], o1, a[g]);
            a[g] = dot2(w1[g][4*r+2], o2, a[g]);
            a[g] = dot2(w1[g][4*r+3], o3, a[g]);
          }
        }
#pragma unroll
        for (int g=0; g<4; ++g){
          const float v = qsum2(qsum1(a[g]));
          a[g] = v + __shfl_xor(v, 4, 64);
        }
        if (xact){                                  // stage x(t+1); refill depth-2
          vhE[nxt*96 + xl] = packh2(xa.x, xa.y);
          xa = xb;
          const int t3 = (t+3 < TT) ? (t+3) : (TT-1);
          xb = *(const float2*)(xrow + t3*128 + 2*xl);
        }
        c1 = sigm(a[1])*c1 + sigm(a[0])*tanh_(a[2]);
        const float h = sigm(a[3])*tanh_(c1);
        if (q1 == 0){
          ((_Float16*)(vhE + nxt*96))[128 + j1] = (_Float16)h;
          ((_Float16*)(rngE + cur*32))[j1] = (_Float16)fmaxf(h, 0.0f);
        }
      }
      // ----- e2 step t2 = t-1
      if (t >= 1 && e2act){
        const int t2 = t-1, c2p = t2 & 1, n2p = c2p ^ 1;
        const unsigned* hrow = rngE + c2p*32;
        const unsigned* vcur = vhE2 + c2p*16;
        float a[4] = {bias2[0], bias2[1], bias2[2], bias2[3]};
#pragma unroll
        for (int r=0;r<3;++r){
          const int dw = 12*q2 + 4*r;
          const unsigned* p = (dw < 32) ? (hrow + dw) : (vcur + (dw - 32));
          const uint4 u = *(const uint4*)p;
          const half2v o0=ash2(u.x), o1=ash2(u.y), o2=ash2(u.z), o3=ash2(u.w);
#pragma unroll
          for (int g=0; g<4; ++g){
            a[g] = dot2(w2[g][4*r+0], o0, a[g]);
            a[g] = dot2(w2[g][4*r+1], o1, a[g]);
            a[g] = dot2(w2[g][4*r+2], o2, a[g]);
            a[g] = dot2(w2[g][4*r+3], o3, a[g]);
          }
        }
#pragma unroll
        for (int g=0; g<4; ++g) a[g] = qsum2(qsum1(a[g]));
        c2 = sigm(a[1])*c2 + sigm(a[0])*tanh_(a[2]);
        const float h = sigm(a[3])*tanh_(c2);
        if (q2 == 0){
          ((_Float16*)(vhE2 + n2p*16))[j2] = (_Float16)h;
          if (t2 == TT-1) latF[j2] = fmaxf(h, 0.0f);
        }
      }
      __syncthreads();
    }
  }
  __syncthreads();
  asm volatile("" ::: "memory");   // keep decoder weight loads below the e-loop

  //======================= DECODER: d1 || d2 (lag 1) =======================
  {
    const int qd = tid & 3, jd = tid >> 2;   // d2: jd in [0,128); d1 (tid<256): jd in [0,64)
    half2v wD2[4][24];
    float biasD2[4];
#pragma unroll
    for (int g=0; g<4; ++g){
      const int row = g*128 + jd;
      biasD2[g] = (qd==0)? (bihD2[row]+bhhD2[row]) : 0.0f;
#pragma unroll
      for (int m=0;m<24;++m){
        const int k0 = 48*qd + 2*m;          // concat {x:64, h:128}
        const float lo = (k0   < 64)? WihD2[row*64+k0]   : WhhD2[row*128+(k0-64)];
        const float hi = (k0+1 < 64)? WihD2[row*64+k0+1] : WhhD2[row*128+(k0+1-64)];
        wD2[g][m] = mkh2(lo,hi);
      }
    }
    const bool d1act = (tid < 256);
    half2v wD1[4][8];
    float projD1[4] = {0.f,0.f,0.f,0.f};
    if (d1act){
#pragma unroll
      for (int g=0; g<4; ++g){
        const int row = g*64 + jd;
#pragma unroll
        for (int m=0;m<8;++m){
          const int k0 = 16*qd + 2*m;        // h only, K=64
          wD1[g][m] = mkh2(WhhD1[row*64+k0], WhhD1[row*64+k0+1]);
        }
        if (qd==0){
          float a = bihD1[row]+bhhD1[row];
#pragma unroll
          for (int i=0;i<16;++i) a = fmaf(WihD1[row*16+i], latF[i], a);
          projD1[g] = a;
        }
      }
    }
    if (tid < 32)               vhD1[tid] = 0u;       // d1 h(-1)=0
    if (tid >= 64 && tid < 128) vhD2[tid-64] = 0u;    // d2 h(-1)=0
    float cd1 = 0.0f, cd2 = 0.0f;
    float* orow = out + (size_t)b * (TT*128);
    __syncthreads();

    for (int t = 0; t <= TT; ++t){
      const int cur = t & 1;
      // ----- d1 step t
      if (t < TT && d1act){
        const int nxt = cur ^ 1;
        float a[4] = {projD1[0],projD1[1],projD1[2],projD1[3]};
        const uint4* vp = (const uint4*)(vhD1 + cur*32 + qd*8);
#pragma unroll
        for (int r=0;r<2;++r){
          const uint4 u = vp[r];
          const half2v o0=ash2(u.x),o1=ash2(u.y),o2=ash2(u.z),o3=ash2(u.w);
#pragma unroll
          for (int g=0; g<4; ++g){
            a[g]=dot2(wD1[g][4*r+0],o0,a[g]);
            a[g]=dot2(wD1[g][4*r+1],o1,a[g]);
            a[g]=dot2(wD1[g][4*r+2],o2,a[g]);
            a[g]=dot2(wD1[g][4*r+3],o3,a[g]);
          }
        }
#pragma unroll
        for (int g=0; g<4; ++g) a[g] = qsum2(qsum1(a[g]));
        cd1 = sigm(a[1])*cd1 + sigm(a[0])*tanh_(a[2]);
        const float h = sigm(a[3])*tanh_(cd1);
        if (qd==0){
          ((_Float16*)(vhD1 + nxt*32))[jd] = (_Float16)h;
          ((_Float16*)(rngD + cur*32))[jd] = (_Float16)fmaxf(h,0.0f);
        }
      }
      // ----- d2 step t2 = t-1
      if (t >= 1){
        const int t2 = t-1, c2p = t2 & 1, n2p = c2p ^ 1;
        const unsigned* hrow = rngD + c2p*32;
        const unsigned* vcur = vhD2 + c2p*64;
        float a[4] = {biasD2[0],biasD2[1],biasD2[2],biasD2[3]};
#pragma unroll
        for (int r=0;r<6;++r){
          const int dw = 24*qd + 4*r;
          const unsigned* p = (dw < 32) ? (hrow + dw) : (vcur + (dw-32));
          const uint4 u = *(const uint4*)p;
          const half2v o0=ash2(u.x),o1=ash2(u.y),o2=ash2(u.z),o3=ash2(u.w);
#pragma unroll
          for (int g=0; g<4; ++g){
            a[g]=dot2(wD2[g][4*r+0],o0,a[g]);
            a[g]=dot2(wD2[g][4*r+1],o1,a[g]);
            a[g]=dot2(wD2[g][4*r+2],o2,a[g]);
            a[g]=dot2(wD2[g][4*r+3],o3,a[g]);
          }
        }
#pragma unroll
        for (int g=0; g<4; ++g) a[g] = qsum2(qsum1(a[g]));
        cd2 = sigm(a[1])*cd2 + sigm(a[0])*tanh_(a[2]);
        const float h = sigm(a[3])*tanh_(cd2);
        if (qd==0){
          ((_Float16*)(vhD2 + n2p*64))[jd] = (_Float16)h;
          orow[(size_t)t2*128 + jd] = h;
        }
      }
      __syncthreads();
    }
  }
}

extern "C" void kernel_launch(void* const* d_in, const int* in_sizes, int n_in,
                              void* d_out, int out_size, void* d_ws, size_t ws_size,
                              hipStream_t stream) {
  const float* x      = (const float*)d_in[0];
  const float* WihE1  = (const float*)d_in[1];
  const float* WhhE1  = (const float*)d_in[2];
  const float* bihE1  = (const float*)d_in[3];
  const float* bhhE1  = (const float*)d_in[4];
  const float* WihE2  = (const float*)d_in[5];
  const float* WhhE2  = (const float*)d_in[6];
  const float* bihE2  = (const float*)d_in[7];
  const float* bhhE2  = (const float*)d_in[8];
  const float* WihD1  = (const float*)d_in[9];
  const float* WhhD1  = (const float*)d_in[10];
  const float* bihD1  = (const float*)d_in[11];
  const float* bhhD1  = (const float*)d_in[12];
  const float* WihD2  = (const float*)d_in[13];
  const float* WhhD2  = (const float*)d_in[14];
  const float* bihD2  = (const float*)d_in[15];
  const float* bhhD2  = (const float*)d_in[16];
  float* out = (float*)d_out;

  k_fused<<<BB, 512, 0, stream>>>(x,
      WihE1, WhhE1, bihE1, bhhE1,
      WihE2, WhhE2, bihE2, bhhE2,
      WihD1, WhhD1, bihD1, bhhD1,
      WihD2, WhhD2, bihD2, bhhD2,
      out);
}

// Round 7
// 838.810 us; speedup vs baseline: 2.2322x; 1.3656x over previous
//
#include <hip/hip_runtime.h>

// LSTM autoencoder, fused single kernel. B=256 blocks (1/CU), 512 thr, lb(512,2).
// e-loop: e1 on waves 0-3 (quad-owns-unit, 4-way k-split, 96 dot2/lane),
//         e2 on wave 4 (lag 1), x-prefetch on wave 7 (depth 2).
// d-loop: d2 on all 8 waves (quad-owns-unit), d1 on waves 0-3 (lag-1 lead).
// Quad-reduce via DPP xor1/xor2; activation SPLIT across quad (lane q
// activates gate q, share via 4 DPP quad-broadcasts) -> 2 transcendentals
// per lane instead of 10. f16x2 weights in regs + v_dot2_f32_f16.
// launch_bounds(512,2) -> 256-VGPR budget: decoder (~170 VGPR) must not
// spill (round-6 spill = 20MB scratch WRITE + L2 reloads on critical path).

#define BB 256
#define TT 512

typedef _Float16 half2v __attribute__((ext_vector_type(2)));

static __device__ __forceinline__ float dot2(half2v a, half2v b, float c){
  return __builtin_amdgcn_fdot2(a,b,c,false);
}
static __device__ __forceinline__ float qsum1(float v){
  int t = __builtin_amdgcn_update_dpp(0, __float_as_int(v), 0xB1, 0xF, 0xF, true);
  return v + __int_as_float(t);
}
static __device__ __forceinline__ float qsum2(float v){
  int t = __builtin_amdgcn_update_dpp(0, __float_as_int(v), 0x4E, 0xF, 0xF, true);
  return v + __int_as_float(t);
}
template<int CTRL>
static __device__ __forceinline__ float qb(float v){
  return __int_as_float(__builtin_amdgcn_update_dpp(0, __float_as_int(v), CTRL, 0xF, 0xF, true));
}
static __device__ __forceinline__ unsigned packh2(float lo, float hi){
  half2v p; p.x=(_Float16)lo; p.y=(_Float16)hi;
  return __builtin_bit_cast(unsigned, p);
}
static __device__ __forceinline__ half2v ash2(unsigned u){ return __builtin_bit_cast(half2v,u); }
static __device__ __forceinline__ half2v mkh2(float lo, float hi){
  half2v p; p.x=(_Float16)lo; p.y=(_Float16)hi; return p;
}

// All quad lanes hold identical a0..a3 = (i,f,g,o). Lane q activates gate q
// (tanh for q==2 via 2*sigm(2v)-1), broadcasts via DPP, updates c, returns h.
static __device__ __forceinline__ float lstm_update(int q, float a0, float a1,
                                                    float a2, float a3, float& c){
  float mine = a0;
  mine = (q==1) ? a1 : mine;
  mine = (q==2) ? a2 : mine;
  mine = (q==3) ? a3 : mine;
  const bool isg = (q==2);
  const float arg = isg ? (mine+mine) : mine;
  const float s   = 1.0f/(1.0f + __expf(-arg));
  const float act = isg ? (s+s-1.0f) : s;
  const float bi = qb<0x00>(act);
  const float bf = qb<0x55>(act);
  const float bg = qb<0xAA>(act);
  const float bo = qb<0xFF>(act);
  c = bf*c + bi*bg;
  const float s2 = 1.0f/(1.0f + __expf(-(c+c)));
  return bo*(s2+s2-1.0f);
}

__global__ void __launch_bounds__(512, 2) k_fused(
    const float* __restrict__ x,
    const float* __restrict__ WihE1, const float* __restrict__ WhhE1,
    const float* __restrict__ bihE1, const float* __restrict__ bhhE1,
    const float* __restrict__ WihE2, const float* __restrict__ WhhE2,
    const float* __restrict__ bihE2, const float* __restrict__ bhhE2,
    const float* __restrict__ WihD1, const float* __restrict__ WhhD1,
    const float* __restrict__ bihD1, const float* __restrict__ bhhD1,
    const float* __restrict__ WihD2, const float* __restrict__ WhhD2,
    const float* __restrict__ bihD2, const float* __restrict__ bhhD2,
    float* __restrict__ out)
{
  const int b = blockIdx.x, tid = threadIdx.x;

  __shared__ unsigned vhE [2*96];  // e1 operand: x(t) 64dw || h1(t-1) 32dw (f16)
  __shared__ unsigned e2op[2*48];  // e2 operand: relu(h1) 32dw || h2 8dw || pad 8dw
  __shared__ unsigned dop [2*96];  // d2 operand: relu(hd1) 32dw || hd2 64dw
  __shared__ unsigned vhD1[2*32];  // d1 h-state (f16)
  __shared__ float    latF[16];

  //======================= ENCODER =======================
  {
    const int q = tid & 3, j = tid >> 2;        // e1: waves 0-3, j in [0,64)
    const bool e1act = (tid < 256);
    half2v w1[4][24];
    float bias1[4] = {0.f,0.f,0.f,0.f};
    if (e1act){
#pragma unroll
      for (int g=0; g<4; ++g){
        const int row = g*64 + j;
        bias1[g] = (q==0) ? (bihE1[row]+bhhE1[row]) : 0.0f;
#pragma unroll
        for (int m=0;m<24;++m){
          const int k0 = 48*q + 2*m;            // concat {x:128, h:64}
          const float lo = (k0   < 128)? WihE1[row*128+k0]   : WhhE1[row*64 + (k0-128)];
          const float hi = (k0+1 < 128)? WihE1[row*128+k0+1] : WhhE1[row*64 + (k0+1-128)];
          w1[g][m] = mkh2(lo,hi);
        }
      }
    }
    // e2: wave 4 (tid 256..319), unit j2 in [0,16), K=96 padded {h1:64,h2:16,pad:16}
    const bool e2act = (tid >= 256 && tid < 320);
    const int q2 = tid & 3, j2 = (tid - 256) >> 2;
    half2v w2[4][12];
    float bias2[4] = {0.f,0.f,0.f,0.f};
    if (e2act){
#pragma unroll
      for (int g=0; g<4; ++g){
        const int row = g*16 + j2;
        bias2[g] = (q2==0) ? (bihE2[row]+bhhE2[row]) : 0.0f;
#pragma unroll
        for (int m=0;m<12;++m){
          const int k0 = 24*q2 + 2*m;
          float lo = 0.0f, hi = 0.0f;
          if (k0 < 64)        lo = WihE2[row*64+k0];
          else if (k0 < 80)   lo = WhhE2[row*16 + (k0-64)];
          if (k0+1 < 64)      hi = WihE2[row*64+k0+1];
          else if (k0+1 < 80) hi = WhhE2[row*16 + (k0+1-64)];
          w2[g][m] = mkh2(lo,hi);
        }
      }
    }
    // x staging: wave 7 (tid 448..511), depth-2 prefetch
    const bool xact = (tid >= 448);
    const int  xl   = tid - 448;
    const float* xrow = x + (size_t)b * (TT*128);
    float2 xa, xb;
    if (xact){
      float2 v0 = *(const float2*)(xrow + 2*xl);
      vhE[xl] = packh2(v0.x, v0.y);             // x(0) -> parity 0
      xa = *(const float2*)(xrow + 1*128 + 2*xl);
      xb = *(const float2*)(xrow + 2*128 + 2*xl);
    }
    if (tid >= 64 && tid < 96)   vhE[64 + (tid-64)] = 0u;  // h1(-1)=0
    if (tid >= 96 && tid < 192)  e2op[tid-96] = 0u;        // h2(-1)+pads=0 (both par.)
    float c1 = 0.0f, c2 = 0.0f;
    __syncthreads();

    for (int t = 0; t <= TT; ++t){
      const int cur = t & 1, nxt = cur ^ 1;
      // ----- e1 step t (waves 0-3)
      if (t < TT && e1act){
        float a0=bias1[0], a1=bias1[1], a2=bias1[2], a3=bias1[3];
        const uint4* vp = (const uint4*)(vhE + cur*96 + q*24);
#pragma unroll
        for (int r=0;r<6;++r){
          const uint4 u = vp[r];
          const half2v o0=ash2(u.x), o1=ash2(u.y), o2=ash2(u.z), o3=ash2(u.w);
          a0=dot2(w1[0][4*r+0],o0,a0); a1=dot2(w1[1][4*r+0],o0,a1);
          a2=dot2(w1[2][4*r+0],o0,a2); a3=dot2(w1[3][4*r+0],o0,a3);
          a0=dot2(w1[0][4*r+1],o1,a0); a1=dot2(w1[1][4*r+1],o1,a1);
          a2=dot2(w1[2][4*r+1],o1,a2); a3=dot2(w1[3][4*r+1],o1,a3);
          a0=dot2(w1[0][4*r+2],o2,a0); a1=dot2(w1[1][4*r+2],o2,a1);
          a2=dot2(w1[2][4*r+2],o2,a2); a3=dot2(w1[3][4*r+2],o2,a3);
          a0=dot2(w1[0][4*r+3],o3,a0); a1=dot2(w1[1][4*r+3],o3,a1);
          a2=dot2(w1[2][4*r+3],o3,a2); a3=dot2(w1[3][4*r+3],o3,a3);
        }
        a0=qsum2(qsum1(a0)); a1=qsum2(qsum1(a1));
        a2=qsum2(qsum1(a2)); a3=qsum2(qsum1(a3));
        const float h = lstm_update(q, a0, a1, a2, a3, c1);
        if (q == 0){
          ((_Float16*)(vhE + nxt*96))[128 + j] = (_Float16)h;
          ((_Float16*)(e2op + cur*48))[j]      = (_Float16)fmaxf(h, 0.0f);
        }
      }
      // ----- x stage x(t+1) (wave 7)
      if (t < TT && xact){
        vhE[nxt*96 + xl] = packh2(xa.x, xa.y);
        xa = xb;
        const int t3 = (t+3 < TT) ? (t+3) : (TT-1);
        xb = *(const float2*)(xrow + (size_t)t3*128 + 2*xl);
      }
      // ----- e2 step t2 = t-1 (wave 4)
      if (t >= 1 && e2act){
        const int t2 = t-1, c2p = t2 & 1, n2p = c2p ^ 1;
        float a0=bias2[0], a1=bias2[1], a2=bias2[2], a3=bias2[3];
        const uint4* vp = (const uint4*)(e2op + c2p*48 + q2*12);
#pragma unroll
        for (int r=0;r<3;++r){
          const uint4 u = vp[r];
          const half2v o0=ash2(u.x), o1=ash2(u.y), o2=ash2(u.z), o3=ash2(u.w);
          a0=dot2(w2[0][4*r+0],o0,a0); a1=dot2(w2[1][4*r+0],o0,a1);
          a2=dot2(w2[2][4*r+0],o0,a2); a3=dot2(w2[3][4*r+0],o0,a3);
          a0=dot2(w2[0][4*r+1],o1,a0); a1=dot2(w2[1][4*r+1],o1,a1);
          a2=dot2(w2[2][4*r+1],o1,a2); a3=dot2(w2[3][4*r+1],o1,a3);
          a0=dot2(w2[0][4*r+2],o2,a0); a1=dot2(w2[1][4*r+2],o2,a1);
          a2=dot2(w2[2][4*r+2],o2,a2); a3=dot2(w2[3][4*r+2],o2,a3);
          a0=dot2(w2[0][4*r+3],o3,a0); a1=dot2(w2[1][4*r+3],o3,a1);
          a2=dot2(w2[2][4*r+3],o3,a2); a3=dot2(w2[3][4*r+3],o3,a3);
        }
        a0=qsum2(qsum1(a0)); a1=qsum2(qsum1(a1));
        a2=qsum2(qsum1(a2)); a3=qsum2(qsum1(a3));
        const float h = lstm_update(q2, a0, a1, a2, a3, c2);
        if (q2 == 0){
          ((_Float16*)(e2op + n2p*48))[64 + j2] = (_Float16)h;
          if (t2 == TT-1) latF[j2] = fmaxf(h, 0.0f);
        }
      }
      __syncthreads();
    }
  }
  __syncthreads();

  //======================= DECODER =======================
  {
    const int qd = tid & 3, jd = tid >> 2;      // d2: jd in [0,128)
    half2v wD2[4][24];
    float biasD2[4];
#pragma unroll
    for (int g=0; g<4; ++g){
      const int row = g*128 + jd;
      biasD2[g] = (qd==0)? (bihD2[row]+bhhD2[row]) : 0.0f;
#pragma unroll
      for (int m=0;m<24;++m){
        const int k0 = 48*qd + 2*m;             // concat {x:64, h:128}
        const float lo = (k0   < 64)? WihD2[row*64+k0]   : WhhD2[row*128+(k0-64)];
        const float hi = (k0+1 < 64)? WihD2[row*64+k0+1] : WhhD2[row*128+(k0+1-64)];
        wD2[g][m] = mkh2(lo,hi);
      }
    }
    const bool d1act = (tid < 256);             // d1: waves 0-3, unit jd in [0,64)
    half2v wD1[4][8];
    float projD1[4] = {0.f,0.f,0.f,0.f};
    if (d1act){
#pragma unroll
      for (int g=0; g<4; ++g){
        const int row = g*64 + jd;
#pragma unroll
        for (int m=0;m<8;++m){
          const int k0 = 16*qd + 2*m;           // h only, K=64
          wD1[g][m] = mkh2(WhhD1[row*64+k0], WhhD1[row*64+k0+1]);
        }
        if (qd==0){
          float a = bihD1[row]+bhhD1[row];
#pragma unroll
          for (int i=0;i<16;++i) a = fmaf(WihD1[row*16+i], latF[i], a);
          projD1[g] = a;
        }
      }
    }
    if (tid < 192)               dop[tid] = 0u;        // hd2(-1)=0 (both parities)
    if (tid >= 192 && tid < 224) vhD1[tid-192] = 0u;   // hd1(-1)=0 (parity 0)
    float cd1 = 0.0f, cd2 = 0.0f;
    float* orow = out + (size_t)b * (TT*128);
    __syncthreads();

    for (int t = 0; t <= TT; ++t){
      const int cur = t & 1;
      // ----- d1 step t (waves 0-3, leads d2 by 1)
      if (t < TT && d1act){
        const int nxt = cur ^ 1;
        float a0=projD1[0], a1=projD1[1], a2=projD1[2], a3=projD1[3];
        const uint4* vp = (const uint4*)(vhD1 + cur*32 + qd*8);
#pragma unroll
        for (int r=0;r<2;++r){
          const uint4 u = vp[r];
          const half2v o0=ash2(u.x),o1=ash2(u.y),o2=ash2(u.z),o3=ash2(u.w);
          a0=dot2(wD1[0][4*r+0],o0,a0); a1=dot2(wD1[1][4*r+0],o0,a1);
          a2=dot2(wD1[2][4*r+0],o0,a2); a3=dot2(wD1[3][4*r+0],o0,a3);
          a0=dot2(wD1[0][4*r+1],o1,a0); a1=dot2(wD1[1][4*r+1],o1,a1);
          a2=dot2(wD1[2][4*r+1],o1,a2); a3=dot2(wD1[3][4*r+1],o1,a3);
          a0=dot2(wD1[0][4*r+2],o2,a0); a1=dot2(wD1[1][4*r+2],o2,a1);
          a2=dot2(wD1[2][4*r+2],o2,a2); a3=dot2(wD1[3][4*r+2],o2,a3);
          a0=dot2(wD1[0][4*r+3],o3,a0); a1=dot2(wD1[1][4*r+3],o3,a1);
          a2=dot2(wD1[2][4*r+3],o3,a2); a3=dot2(wD1[3][4*r+3],o3,a3);
        }
        a0=qsum2(qsum1(a0)); a1=qsum2(qsum1(a1));
        a2=qsum2(qsum1(a2)); a3=qsum2(qsum1(a3));
        const float h = lstm_update(qd, a0, a1, a2, a3, cd1);
        if (qd==0){
          ((_Float16*)(vhD1 + nxt*32))[jd] = (_Float16)h;
          ((_Float16*)(dop + cur*96))[jd]  = (_Float16)fmaxf(h,0.0f);
        }
      }
      // ----- d2 step t2 = t-1 (all waves)
      if (t >= 1){
        const int t2 = t-1, c2p = t2 & 1, n2p = c2p ^ 1;
        float a0=biasD2[0], a1=biasD2[1], a2=biasD2[2], a3=biasD2[3];
        const uint4* vp = (const uint4*)(dop + c2p*96 + qd*24);
#pragma unroll
        for (int r=0;r<6;++r){
          const uint4 u = vp[r];
          const half2v o0=ash2(u.x),o1=ash2(u.y),o2=ash2(u.z),o3=ash2(u.w);
          a0=dot2(wD2[0][4*r+0],o0,a0); a1=dot2(wD2[1][4*r+0],o0,a1);
          a2=dot2(wD2[2][4*r+0],o0,a2); a3=dot2(wD2[3][4*r+0],o0,a3);
          a0=dot2(wD2[0][4*r+1],o1,a0); a1=dot2(wD2[1][4*r+1],o1,a1);
          a2=dot2(wD2[2][4*r+1],o1,a2); a3=dot2(wD2[3][4*r+1],o1,a3);
          a0=dot2(wD2[0][4*r+2],o2,a0); a1=dot2(wD2[1][4*r+2],o2,a1);
          a2=dot2(wD2[2][4*r+2],o2,a2); a3=dot2(wD2[3][4*r+2],o2,a3);
          a0=dot2(wD2[0][4*r+3],o3,a0); a1=dot2(wD2[1][4*r+3],o3,a1);
          a2=dot2(wD2[2][4*r+3],o3,a2); a3=dot2(wD2[3][4*r+3],o3,a3);
        }
        a0=qsum2(qsum1(a0)); a1=qsum2(qsum1(a1));
        a2=qsum2(qsum1(a2)); a3=qsum2(qsum1(a3));
        const float h = lstm_update(qd, a0, a1, a2, a3, cd2);
        if (qd==0){
          ((_Float16*)(dop + n2p*96))[64 + jd] = (_Float16)h;
          orow[(size_t)t2*128 + jd] = h;
        }
      }
      __syncthreads();
    }
  }
}

extern "C" void kernel_launch(void* const* d_in, const int* in_sizes, int n_in,
                              void* d_out, int out_size, void* d_ws, size_t ws_size,
                              hipStream_t stream) {
  const float* x      = (const float*)d_in[0];
  const float* WihE1  = (const float*)d_in[1];
  const float* WhhE1  = (const float*)d_in[2];
  const float* bihE1  = (const float*)d_in[3];
  const float* bhhE1  = (const float*)d_in[4];
  const float* WihE2  = (const float*)d_in[5];
  const float* WhhE2  = (const float*)d_in[6];
  const float* bihE2  = (const float*)d_in[7];
  const float* bhhE2  = (const float*)d_in[8];
  const float* WihD1  = (const float*)d_in[9];
  const float* WhhD1  = (const float*)d_in[10];
  const float* bihD1  = (const float*)d_in[11];
  const float* bhhD1  = (const float*)d_in[12];
  const float* WihD2  = (const float*)d_in[13];
  const float* WhhD2  = (const float*)d_in[14];
  const float* bihD2  = (const float*)d_in[15];
  const float* bhhD2  = (const float*)d_in[16];
  float* out = (float*)d_out;

  k_fused<<<BB, 512, 0, stream>>>(x,
      WihE1, WhhE1, bihE1, bhhE1,
      WihE2, WhhE2, bihE2, bhhE2,
      WihD1, WhhD1, bihD1, bhhD1,
      WihD2, WhhD2, bihD2, bhhD2,
      out);
}